// Round 1
// baseline (458.929 us; speedup 1.0000x reference)
//
#include <hip/hip_runtime.h>

// Problem constants
#define M_TOT   16384      // 8*2048 rows
#define DM      1024       // d_model
#define CD      64         // code_depth
#define NCODES  8192

// Output layout (fp32, concatenated in return order)
#define SOFT_OFF  0
#define IDX_OFF   1048576            // 16384*64
#define HARD_OFF  1064960            // + 16384
#define LOSS_OFF  2113536            // + 16384*64

// ---------------------------------------------------------------------------
// Kernel 0: c2[k] = ||book_k||^2
// ---------------------------------------------------------------------------
__global__ __launch_bounds__(256) void compute_c2(const float* __restrict__ book,
                                                  float* __restrict__ c2) {
    const int k = blockIdx.x * 256 + threadIdx.x;
    const float4* p = (const float4*)(book + (size_t)k * CD);
    float s = 0.0f;
#pragma unroll
    for (int q = 0; q < CD / 4; ++q) {
        const float4 v = p[q];
        s = fmaf(v.x, v.x, s);
        s = fmaf(v.y, v.y, s);
        s = fmaf(v.z, v.z, s);
        s = fmaf(v.w, v.w, s);
    }
    c2[k] = s;
}

// ---------------------------------------------------------------------------
// Kernel 1: soft = x @ W^T + b   (M=16384, K=1024, N=64)
// 64 rows x 64 cols per block, 256 threads, 4x4 per thread, BK=32
// ---------------------------------------------------------------------------
__global__ __launch_bounds__(256) void soft_gemm(const float* __restrict__ x,
                                                 const float* __restrict__ W,
                                                 const float* __restrict__ bias,
                                                 float* __restrict__ out_soft) {
    __shared__ float xt[32][68];  // xt[kk][row]
    __shared__ float wt[32][68];  // wt[kk][col]

    const int tid = threadIdx.x;
    const int r0  = blockIdx.x * 64;
    const int cg  = tid & 15;   // col group: cols cg*4..+3
    const int rg  = tid >> 4;   // row group: rows rg*4..+3

    float acc[4][4] = {};

    for (int k0 = 0; k0 < DM; k0 += 32) {
#pragma unroll
        for (int i = 0; i < 2; ++i) {
            const int f   = tid + i * 256;       // 0..511
            const int row = f >> 3;              // 0..63
            const int kq  = (f & 7) * 4;         // 0..28
            const float4 v = *(const float4*)(x + (size_t)(r0 + row) * DM + k0 + kq);
            xt[kq + 0][row] = v.x; xt[kq + 1][row] = v.y;
            xt[kq + 2][row] = v.z; xt[kq + 3][row] = v.w;
            const float4 w = *(const float4*)(W + (size_t)row * DM + k0 + kq); // row == col index c
            wt[kq + 0][row] = w.x; wt[kq + 1][row] = w.y;
            wt[kq + 2][row] = w.z; wt[kq + 3][row] = w.w;
        }
        __syncthreads();
#pragma unroll 8
        for (int kk = 0; kk < 32; ++kk) {
            const float4 xv = *(const float4*)&xt[kk][rg * 4];
            const float4 wv = *(const float4*)&wt[kk][cg * 4];
            const float xa[4] = {xv.x, xv.y, xv.z, xv.w};
            const float wa[4] = {wv.x, wv.y, wv.z, wv.w};
#pragma unroll
            for (int r = 0; r < 4; ++r)
#pragma unroll
                for (int q = 0; q < 4; ++q)
                    acc[r][q] = fmaf(xa[r], wa[q], acc[r][q]);
        }
        __syncthreads();
    }

    const float4 bb = *(const float4*)(bias + cg * 4);
#pragma unroll
    for (int r = 0; r < 4; ++r) {
        float4 o;
        o.x = acc[r][0] + bb.x; o.y = acc[r][1] + bb.y;
        o.z = acc[r][2] + bb.z; o.w = acc[r][3] + bb.w;
        *(float4*)(out_soft + (size_t)(r0 + rg * 4 + r) * CD + cg * 4) = o;
    }
}

// ---------------------------------------------------------------------------
// Kernel 2: per-row argmin_k of (c2[k] - 2*soft.book_k)
// grid (256 row-blocks, 2 code-splits); block: 64 rows x 4096 codes
// per-tile: 128 codes staged in LDS; per-thread 4 rows x 8 codes
// ---------------------------------------------------------------------------
__global__ __launch_bounds__(256) void dist_argmin(const float* __restrict__ soft,
                                                   const float* __restrict__ book,
                                                   const float* __restrict__ c2,
                                                   float* __restrict__ cand_d,
                                                   int* __restrict__ cand_i) {
    __shared__ float st[64][68];    // st[d][row]
    __shared__ float bt[64][132];   // bt[d][code]
    __shared__ float c2s[128];
    __shared__ float redd[16][64];
    __shared__ int   redi[16][64];

    const int tid   = threadIdx.x;
    const int r0    = blockIdx.x * 64;
    const int kbase = blockIdx.y * (NCODES / 2);

    // stage soft tile (transposed)
#pragma unroll
    for (int i = 0; i < 4; ++i) {
        const int f   = tid + i * 256;       // 0..1023
        const int row = f >> 4;              // 0..63
        const int dq  = (f & 15) * 4;        // 0..60
        const float4 v = *(const float4*)(soft + (size_t)(r0 + row) * CD + dq);
        st[dq + 0][row] = v.x; st[dq + 1][row] = v.y;
        st[dq + 2][row] = v.z; st[dq + 3][row] = v.w;
    }

    const int rg = tid & 15;   // rows rg*4..+3
    const int kg = tid >> 4;   // codes kg*8..+7 within tile

    float mind[4] = {3.4e38f, 3.4e38f, 3.4e38f, 3.4e38f};
    int   mini[4] = {0, 0, 0, 0};

    for (int kt = 0; kt < NCODES / 2; kt += 128) {
        // stage book tile (transposed): 128 codes x 64 dims
#pragma unroll
        for (int i = 0; i < 8; ++i) {
            const int f    = tid + i * 256;   // 0..2047
            const int code = f >> 4;          // 0..127
            const int dq   = (f & 15) * 4;    // 0..60
            const float4 v = *(const float4*)(book + (size_t)(kbase + kt + code) * CD + dq);
            bt[dq + 0][code] = v.x; bt[dq + 1][code] = v.y;
            bt[dq + 2][code] = v.z; bt[dq + 3][code] = v.w;
        }
        if (tid < 128) c2s[tid] = c2[kbase + kt + tid];
        __syncthreads();

        float acc[4][8] = {};
#pragma unroll 4
        for (int d = 0; d < 64; ++d) {
            const float4 s  = *(const float4*)&st[d][rg * 4];
            const float4 b0 = *(const float4*)&bt[d][kg * 8];
            const float4 b1 = *(const float4*)&bt[d][kg * 8 + 4];
            const float sv[4] = {s.x, s.y, s.z, s.w};
            const float bv[8] = {b0.x, b0.y, b0.z, b0.w, b1.x, b1.y, b1.z, b1.w};
#pragma unroll
            for (int r = 0; r < 4; ++r)
#pragma unroll
                for (int j = 0; j < 8; ++j)
                    acc[r][j] = fmaf(sv[r], bv[j], acc[r][j]);
        }
        __syncthreads();

        // fold this tile into the running argmin (codes ascending -> first-wins ties)
#pragma unroll
        for (int j = 0; j < 8; ++j) {
            const int   kidx = kbase + kt + kg * 8 + j;
            const float cc   = c2s[kg * 8 + j];
#pragma unroll
            for (int r = 0; r < 4; ++r) {
                const float dd = fmaf(-2.0f, acc[r][j], cc);
                if (dd < mind[r]) { mind[r] = dd; mini[r] = kidx; }
            }
        }
    }

    // reduce across the 16 code-groups per row
#pragma unroll
    for (int r = 0; r < 4; ++r) {
        redd[kg][rg * 4 + r] = mind[r];
        redi[kg][rg * 4 + r] = mini[r];
    }
    __syncthreads();
    if (tid < 64) {
        float bd = redd[0][tid];
        int   bi = redi[0][tid];
#pragma unroll
        for (int g = 1; g < 16; ++g) {
            const float dd = redd[g][tid];
            if (dd < bd) { bd = dd; bi = redi[g][tid]; }  // ascending kg => ascending idx
        }
        cand_d[blockIdx.y * M_TOT + r0 + tid] = bd;
        cand_i[blockIdx.y * M_TOT + r0 + tid] = bi;
    }
}

// ---------------------------------------------------------------------------
// Kernel 3: combine splits, gather hard, write idx/ste, accumulate losses
// block = 256 threads = 16 rows x 16 dim-quads
// ---------------------------------------------------------------------------
__global__ __launch_bounds__(256) void finalize(const float* __restrict__ book,
                                                const float* __restrict__ cand_d,
                                                const int* __restrict__ cand_i,
                                                float* __restrict__ out) {
    __shared__ float red[256];
    const int tid = threadIdx.x;
    const int row = blockIdx.x * 16 + (tid >> 4);
    const int dq  = (tid & 15) * 4;

    const float d0 = cand_d[row];
    const float d1 = cand_d[M_TOT + row];
    const int   i0 = cand_i[row];
    const int   i1 = cand_i[M_TOT + row];
    const int   k  = (d1 < d0) ? i1 : i0;   // tie -> split 0 (smaller index)

    if (dq == 0) out[IDX_OFF + row] = (float)k;

    const float4 h = *(const float4*)(book + (size_t)k * CD + dq);
    const float4 s = *(const float4*)(out + SOFT_OFF + (size_t)row * CD + dq);

    const float dx = h.x - s.x, dy = h.y - s.y, dz = h.z - s.z, dw = h.w - s.w;
    float4 ste;  // mirror ref expression soft + (hard - soft)
    ste.x = s.x + dx; ste.y = s.y + dy; ste.z = s.z + dz; ste.w = s.w + dw;
    *(float4*)(out + HARD_OFF + (size_t)row * CD + dq) = ste;

    red[tid] = dx * dx + dy * dy + dz * dz + dw * dw;
    __syncthreads();
#pragma unroll
    for (int sh = 128; sh > 0; sh >>= 1) {
        if (tid < sh) red[tid] += red[tid + sh];
        __syncthreads();
    }
    if (tid == 0) {
        const float v = red[0] * (1.0f / (float)(M_TOT * CD));
        atomicAdd(out + LOSS_OFF, v);      // commitment
        atomicAdd(out + LOSS_OFF + 1, v);  // embedding (numerically identical)
    }
}

// ---------------------------------------------------------------------------
extern "C" void kernel_launch(void* const* d_in, const int* in_sizes, int n_in,
                              void* d_out, int out_size, void* d_ws, size_t ws_size,
                              hipStream_t stream) {
    const float* x    = (const float*)d_in[0];
    const float* W    = (const float*)d_in[1];
    const float* bias = (const float*)d_in[2];
    const float* book = (const float*)d_in[3];  // [1][8192][64] == flat [8192][64]
    float* out = (float*)d_out;

    float* ws     = (float*)d_ws;
    float* c2     = ws;                         // 8192 floats
    float* cand_d = ws + NCODES;                // 2*16384 floats
    int*   cand_i = (int*)(ws + NCODES + 2 * M_TOT);  // 2*16384 ints

    compute_c2<<<NCODES / 256, 256, 0, stream>>>(book, c2);
    soft_gemm<<<M_TOT / 64, 256, 0, stream>>>(x, W, bias, out + SOFT_OFF);
    dist_argmin<<<dim3(M_TOT / 64, 2), 256, 0, stream>>>(out + SOFT_OFF, book, c2,
                                                         cand_d, cand_i);
    hipMemsetAsync(out + LOSS_OFF, 0, 2 * sizeof(float), stream);
    finalize<<<M_TOT / 16, 256, 0, stream>>>(book, cand_d, cand_i, out);
}